// Round 3
// baseline (265.621 us; speedup 1.0000x reference)
//
#include <hip/hip_runtime.h>
#include <hip/hip_bf16.h>

// RBF: out[n, i, 0] = exp(-||x_cur[n]     - c_i||^2 / beta)
//      out[n, i, 1] = exp(-||x_delayed[n] - c_i||^2 / beta)
// N=8192 rows, M=4096 centres, IN=2, beta=0.04.
// Output 8192*4096*2 f32 = 256 MB -> pure streaming-write bound (~41 us floor).
//
// Structure: 2048 blocks = 8 column-groups x 256 row-groups.
//   Each thread owns ONE float4 centre chunk (2 centres) in REGISTERS,
//   reused across 32 rows -> centres read once per block (4 KB), not per row.
//   Output stores are nontemporal (zero reuse, don't churn L2).

#define N_STEPS      8192
#define OUT_F4       2048   // float4 outputs per row = OUT_FEATURES*2/4
#define ROWS_PER_BLK 32
#define COL_GROUPS   8      // 2048 f4 cols / 256 threads

typedef float f32x4 __attribute__((ext_vector_type(4)));

__global__ __launch_bounds__(256) void
RBF_36404142801269_kernel(const float* __restrict__ x_cur,
                          const float* __restrict__ x_delayed,
                          const float* __restrict__ centres,
                          float* __restrict__ out) {
    const int cg = blockIdx.x & (COL_GROUPS - 1);          // column group 0..7
    const int r0 = (blockIdx.x >> 3) * ROWS_PER_BLK;       // first row of this block
    const int j  = cg * 256 + threadIdx.x;                 // this thread's f4 column

    // This thread's 2 centres, loaded ONCE and held in registers.
    const f32x4 c = ((const f32x4*)centres)[j];

    // exp(-d2/beta) = exp2(d2 * COEF)
    const float COEF = -1.44269504088896f / 0.04f;

    f32x4* __restrict__ ov = (f32x4*)out;

    #pragma unroll 4
    for (int n = r0; n < r0 + ROWS_PER_BLK; ++n) {
        // Wave-uniform per-row query points (scalar loads, x arrays L2-resident).
        const float xc0 = x_cur[2 * n + 0];
        const float xc1 = x_cur[2 * n + 1];
        const float xd0 = x_delayed[2 * n + 0];
        const float xd1 = x_delayed[2 * n + 1];

        // centre A = (c.x, c.y)
        float a0 = xc0 - c.x, a1 = xc1 - c.y;
        const float sA_now = a0 * a0 + a1 * a1;
        a0 = xd0 - c.x; a1 = xd1 - c.y;
        const float sA_del = a0 * a0 + a1 * a1;

        // centre B = (c.z, c.w)
        float b0 = xc0 - c.z, b1 = xc1 - c.w;
        const float sB_now = b0 * b0 + b1 * b1;
        b0 = xd0 - c.z; b1 = xd1 - c.w;
        const float sB_del = b0 * b0 + b1 * b1;

        f32x4 o;
        o.x = __builtin_amdgcn_exp2f(sA_now * COEF);  // k_now(2j)
        o.y = __builtin_amdgcn_exp2f(sA_del * COEF);  // k_del(2j)
        o.z = __builtin_amdgcn_exp2f(sB_now * COEF);  // k_now(2j+1)
        o.w = __builtin_amdgcn_exp2f(sB_del * COEF);  // k_del(2j+1)

        __builtin_nontemporal_store(o, &ov[(size_t)n * OUT_F4 + j]);
    }
}

extern "C" void kernel_launch(void* const* d_in, const int* in_sizes, int n_in,
                              void* d_out, int out_size, void* d_ws, size_t ws_size,
                              hipStream_t stream) {
    const float* x_cur     = (const float*)d_in[0];
    const float* x_delayed = (const float*)d_in[1];
    const float* centres   = (const float*)d_in[2];
    float* out             = (float*)d_out;

    const int n_blocks = (N_STEPS / ROWS_PER_BLK) * COL_GROUPS;  // 2048
    RBF_36404142801269_kernel<<<n_blocks, 256, 0, stream>>>(x_cur, x_delayed, centres, out);
}